// Round 3
// baseline (378.980 us; speedup 1.0000x reference)
//
#include <hip/hip_runtime.h>
#include <hip/hip_bf16.h>

// StyleLoss — x (1,512,64,64) fp32, target (512,256,256) fp32 -> scalar loss.
// loss = mean_{i,a,b}( (g_full[(i+a)%512,(i+b)%512]/2^20 - target[i,a,b])^2 ) * 1e6
// g_full = feats @ feats^T, feats = x reshaped (512, 4096), bf16 MFMA (tol ~2%).
//
// ws layout: [0,4MB) bf16 feats; [4MB,8MB) fp32 g_part[4][512*512]; [8MB,9MB) fp32 g_full.

typedef __attribute__((ext_vector_type(8))) short bf16x8;   // 8 bf16 in 4 VGPRs
typedef __attribute__((ext_vector_type(4))) float f32x4;

#define CH 512
#define KDIM 4096
#define FEATS_ELEMS (CH * KDIM)
#define SPLITK 4

// ---------------------------------------------------------------- convert ----
__global__ __launch_bounds__(256) void convert_kernel(const float* __restrict__ x,
                                                      __hip_bfloat16* __restrict__ feats) {
    int idx = blockIdx.x * 256 + threadIdx.x;   // 262144 threads, 8 elems each
    const float4* x4 = (const float4*)x;
    float4 v0 = x4[idx * 2 + 0];
    float4 v1 = x4[idx * 2 + 1];
    float f[8] = {v0.x, v0.y, v0.z, v0.w, v1.x, v1.y, v1.z, v1.w};
    union { ushort u[8]; uint4 v; } o;
#pragma unroll
    for (int i = 0; i < 8; ++i) {
        __hip_bfloat16 b = __float2bfloat16(f[i]);
        o.u[i] = *reinterpret_cast<ushort*>(&b);
    }
    *reinterpret_cast<uint4*>(feats + idx * 8) = o.v;
}

// ---------------------------------------------------------------- gemm -------
// C = F * F^T, F 512x4096 bf16 row-major. 64x64 tile, BK=64, split-K=4
// (256 blocks), register prefetch, PLAIN stores into private slice g_part[kz]
// (round-2 lesson: 2.1M atomicAdds into 256K addrs cost ~150 us).
#define BM 64
#define BK 64
#define LDT 72   // padded LDS stride in bf16: 144 B (b128-aligned, 2-way alias = free)

__global__ __launch_bounds__(256) void gemm_kernel(const __hip_bfloat16* __restrict__ feats,
                                                   float* __restrict__ g_part) {
    __shared__ __hip_bfloat16 a_tile[BM * LDT];
    __shared__ __hip_bfloat16 b_tile[BM * LDT];

    const int bm = blockIdx.x, bn = blockIdx.y, kz = blockIdx.z;
    const int tid  = threadIdx.x;
    const int lane = tid & 63;
    const int w    = tid >> 6;        // wave 0..3 -> M rows w*16..w*16+15
    const int m    = lane & 15;
    const int q    = lane >> 4;       // quad: k offset q*8

    const int srow = tid >> 3;        // staging row 0..31 (+32 for p=1)
    const int scol = (tid & 7) * 8;   // 0..56 step 8

    f32x4 acc[4] = {};                // 4 N-subtiles of 16 cols

    const int NT = (KDIM / SPLITK) / BK;            // 16 k-tiles per block
    const int k0base = kz * (KDIM / SPLITK);        // 1024 per split

    const __hip_bfloat16* arow0 = feats + (size_t)(bm * 64 + srow) * KDIM + k0base + scol;
    const __hip_bfloat16* brow0 = feats + (size_t)(bn * 64 + srow) * KDIM + k0base + scol;

    uint4 pa[2], pb[2];
#pragma unroll
    for (int p = 0; p < 2; ++p) {
        pa[p] = *(const uint4*)(arow0 + (size_t)p * 32 * KDIM);
        pb[p] = *(const uint4*)(brow0 + (size_t)p * 32 * KDIM);
    }

    for (int kt = 0; kt < NT; ++kt) {
        if (kt > 0) __syncthreads();               // previous MFMA reads done
#pragma unroll
        for (int p = 0; p < 2; ++p) {
            uint* ap = (uint*)(a_tile + (srow + p * 32) * LDT + scol);
            ap[0] = pa[p].x; ap[1] = pa[p].y; ap[2] = pa[p].z; ap[3] = pa[p].w;
            uint* bp = (uint*)(b_tile + (srow + p * 32) * LDT + scol);
            bp[0] = pb[p].x; bp[1] = pb[p].y; bp[2] = pb[p].z; bp[3] = pb[p].w;
        }
        __syncthreads();
        if (kt + 1 < NT) {                         // prefetch next tile (overlaps MFMA)
            const int ko = (kt + 1) * BK;
#pragma unroll
            for (int p = 0; p < 2; ++p) {
                pa[p] = *(const uint4*)(arow0 + (size_t)p * 32 * KDIM + ko);
                pb[p] = *(const uint4*)(brow0 + (size_t)p * 32 * KDIM + ko);
            }
        }
#pragma unroll
        for (int ks = 0; ks < 2; ++ks) {
            const int kk = ks * 32 + q * 8;
            bf16x8 afrag = *(const bf16x8*)(a_tile + (w * 16 + m) * LDT + kk);
#pragma unroll
            for (int j = 0; j < 4; ++j) {
                bf16x8 bfrag = *(const bf16x8*)(b_tile + (j * 16 + m) * LDT + kk);
                acc[j] = __builtin_amdgcn_mfma_f32_16x16x32_bf16(afrag, bfrag, acc[j], 0, 0, 0);
            }
        }
    }

    // Epilogue: C/D layout col = lane&15, row = (lane>>4)*4 + reg (verified m89/m91)
    float* gp = g_part + ((size_t)kz << 18);
    const int col = lane & 15;
    const int rq  = (lane >> 4) * 4;
#pragma unroll
    for (int j = 0; j < 4; ++j) {
#pragma unroll
        for (int reg = 0; reg < 4; ++reg) {
            const int rg = bm * 64 + w * 16 + rq + reg;
            const int cg = bn * 64 + j * 16 + col;
            gp[rg * CH + cg] = acc[j][reg];
        }
    }
}

// ---------------------------------------------------------------- reduce -----
// g_full = sum of 4 split-K slices. 65536 threads x 1 float4.
__global__ __launch_bounds__(256) void reduce_kernel(const float* __restrict__ g_part,
                                                     float* __restrict__ g_full) {
    int t = blockIdx.x * 256 + threadIdx.x;       // 0..65535
    const float4* p = (const float4*)g_part;
    float4 s = p[t];
#pragma unroll
    for (int sl = 1; sl < SPLITK; ++sl) {
        float4 v = p[t + sl * 65536];
        s.x += v.x; s.y += v.y; s.z += v.z; s.w += v.w;
    }
    ((float4*)g_full)[t] = s;
}

// ---------------------------------------------------------------- loss -------
// 4096 blocks: i = blk>>3 (gram diag index), a-window a0 = (blk&7)*32.
// Stage the needed 32x256 g segment in LDS (g_seg[a][m] = g[(i+a0+a)&511][(i+m)&511]),
// then inner loop is coalesced float4 target stream + aligned ds_read_b128.
// tv loads issued BEFORE staging -> 8 global loads in flight per thread.
__global__ __launch_bounds__(256, 4) void loss_kernel(const float* __restrict__ target,
                                                      const float* __restrict__ g_full,
                                                      float* __restrict__ out) {
    const float gscale = 1.0f / 1048576.0f;          // 1/(b*local_ch*w*h)
    const float lscale = 1.0e6f / 33554432.0f;       // WEIGHT / count

    __shared__ float g_seg[32][260];                 // 33280 B -> 4 blocks/CU

    const int tid  = threadIdx.x;
    const int lane = tid & 63;
    const int wv   = tid >> 6;
    const int blk  = blockIdx.x;
    const int i    = blk >> 3;
    const int a0   = (blk & 7) * 32;

    // ---- issue the target stream loads first (independent of LDS) ----
    const float4* t4 = (const float4*)target + (i << 14) + (a0 << 6);
    float4 tv[8];
#pragma unroll
    for (int j = 0; j < 8; ++j) tv[j] = t4[j * 256 + tid];

    // ---- stage g segment: row a (cooperative, coalesced, 8-deep batches) ----
    const int colg = (i + tid) & 511;
#pragma unroll
    for (int it = 0; it < 32; it += 8) {
        float v[8];
#pragma unroll
        for (int u = 0; u < 8; ++u)
            v[u] = g_full[(((i + a0 + it + u) & 511) << 9) + colg];
#pragma unroll
        for (int u = 0; u < 8; ++u)
            g_seg[it + u][tid] = v[u];
    }
    __syncthreads();

    // ---- main: per j, wave wv handles row a_local = j*4+wv, lane L cols 4L..4L+3
    float4 gv[8];
#pragma unroll
    for (int j = 0; j < 8; ++j)
        gv[j] = *(const float4*)&g_seg[j * 4 + wv][lane * 4];

    float acc = 0.0f;
#pragma unroll
    for (int j = 0; j < 8; ++j) {
        float d0 = __builtin_fmaf(gv[j].x, gscale, -tv[j].x);
        float d1 = __builtin_fmaf(gv[j].y, gscale, -tv[j].y);
        float d2 = __builtin_fmaf(gv[j].z, gscale, -tv[j].z);
        float d3 = __builtin_fmaf(gv[j].w, gscale, -tv[j].w);
        acc += d0 * d0 + d1 * d1 + d2 * d2 + d3 * d3;
    }

    // wave-64 butterfly reduce, then one atomic per wave
#pragma unroll
    for (int off = 32; off > 0; off >>= 1) acc += __shfl_xor(acc, off, 64);
    if (lane == 0) atomicAdd(out, acc * lscale);
}

// ---------------------------------------------------------------- launch -----
extern "C" void kernel_launch(void* const* d_in, const int* in_sizes, int n_in,
                              void* d_out, int out_size, void* d_ws, size_t ws_size,
                              hipStream_t stream) {
    const float* x      = (const float*)d_in[0];   // 2097152 fp32
    const float* target = (const float*)d_in[1];   // 33554432 fp32
    float* out = (float*)d_out;

    __hip_bfloat16* feats = (__hip_bfloat16*)d_ws;                        // 4 MB
    float* g_part = (float*)((char*)d_ws + FEATS_ELEMS * sizeof(__hip_bfloat16)); // 4 MB
    float* g_full = g_part + SPLITK * CH * CH;                            // 1 MB

    hipMemsetAsync(d_out, 0, sizeof(float), stream);

    convert_kernel<<<FEATS_ELEMS / (256 * 8), 256, 0, stream>>>(x, feats);
    gemm_kernel<<<dim3(CH / BM, CH / BM, SPLITK), 256, 0, stream>>>(feats, g_part);
    reduce_kernel<<<CH * CH / 4 / 256, 256, 0, stream>>>(g_part, g_full);
    loss_kernel<<<4096, 256, 0, stream>>>(target, g_full, out);
}

// Round 4
// 213.253 us; speedup vs baseline: 1.7771x; 1.7771x over previous
//
#include <hip/hip_runtime.h>
#include <hip/hip_bf16.h>

// StyleLoss — x (1,512,64,64) fp32, target (512,256,256) fp32 -> scalar loss.
// loss = mean_{i,a,b}( (g_full[(i+a)%512,(i+b)%512]/2^20 - target[i,a,b])^2 ) * 1e6
// g_full = feats @ feats^T, feats = x reshaped (512, 4096), bf16 MFMA (tol ~2%).
//
// R3 lesson: loss dur == 13.5 ns x (same-address atomicAdd count) in EVERY round
// -> the single-address atomic chain was the bottleneck, not memory. This round:
// zero atomics (block partials + 1-block finish).
//
// ws: [0,4MB) bf16 feats; [4,8MB) fp32 g_part[4][512*512]; [8,9MB) fp32 g_full;
//     [9MB,+8KB) fp32 partials[2048].

typedef __attribute__((ext_vector_type(8))) short bf16x8;   // 8 bf16 in 4 VGPRs
typedef __attribute__((ext_vector_type(4))) float f32x4;

#define CH 512
#define KDIM 4096
#define FEATS_ELEMS (CH * KDIM)
#define SPLITK 4
#define LOSS_BLOCKS 2048

// ---------------------------------------------------------------- convert ----
__global__ __launch_bounds__(256) void convert_kernel(const float* __restrict__ x,
                                                      __hip_bfloat16* __restrict__ feats) {
    int idx = blockIdx.x * 256 + threadIdx.x;   // 262144 threads, 8 elems each
    const float4* x4 = (const float4*)x;
    float4 v0 = x4[idx * 2 + 0];
    float4 v1 = x4[idx * 2 + 1];
    float f[8] = {v0.x, v0.y, v0.z, v0.w, v1.x, v1.y, v1.z, v1.w};
    union { ushort u[8]; uint4 v; } o;
#pragma unroll
    for (int i = 0; i < 8; ++i) {
        __hip_bfloat16 b = __float2bfloat16(f[i]);
        o.u[i] = *reinterpret_cast<ushort*>(&b);
    }
    *reinterpret_cast<uint4*>(feats + idx * 8) = o.v;
}

// ---------------------------------------------------------------- gemm -------
// C = F * F^T, F 512x4096 bf16 row-major. 64x64 tile, BK=64, split-K=4
// (256 blocks), register prefetch, plain stores into private slice g_part[kz].
#define BM 64
#define BK 64
#define LDT 72   // padded LDS stride in bf16: 144 B (b128-aligned, 2-way alias = free)

__global__ __launch_bounds__(256) void gemm_kernel(const __hip_bfloat16* __restrict__ feats,
                                                   float* __restrict__ g_part) {
    __shared__ __hip_bfloat16 a_tile[BM * LDT];
    __shared__ __hip_bfloat16 b_tile[BM * LDT];

    const int bm = blockIdx.x, bn = blockIdx.y, kz = blockIdx.z;
    const int tid  = threadIdx.x;
    const int lane = tid & 63;
    const int w    = tid >> 6;        // wave 0..3 -> M rows w*16..w*16+15
    const int m    = lane & 15;
    const int q    = lane >> 4;       // quad: k offset q*8

    const int srow = tid >> 3;        // staging row 0..31 (+32 for p=1)
    const int scol = (tid & 7) * 8;   // 0..56 step 8

    f32x4 acc[4] = {};                // 4 N-subtiles of 16 cols

    const int NT = (KDIM / SPLITK) / BK;            // 16 k-tiles per block
    const int k0base = kz * (KDIM / SPLITK);        // 1024 per split

    const __hip_bfloat16* arow0 = feats + (size_t)(bm * 64 + srow) * KDIM + k0base + scol;
    const __hip_bfloat16* brow0 = feats + (size_t)(bn * 64 + srow) * KDIM + k0base + scol;

    uint4 pa[2], pb[2];
#pragma unroll
    for (int p = 0; p < 2; ++p) {
        pa[p] = *(const uint4*)(arow0 + (size_t)p * 32 * KDIM);
        pb[p] = *(const uint4*)(brow0 + (size_t)p * 32 * KDIM);
    }

    for (int kt = 0; kt < NT; ++kt) {
        if (kt > 0) __syncthreads();               // previous MFMA reads done
#pragma unroll
        for (int p = 0; p < 2; ++p) {
            uint* ap = (uint*)(a_tile + (srow + p * 32) * LDT + scol);
            ap[0] = pa[p].x; ap[1] = pa[p].y; ap[2] = pa[p].z; ap[3] = pa[p].w;
            uint* bp = (uint*)(b_tile + (srow + p * 32) * LDT + scol);
            bp[0] = pb[p].x; bp[1] = pb[p].y; bp[2] = pb[p].z; bp[3] = pb[p].w;
        }
        __syncthreads();
        if (kt + 1 < NT) {                         // prefetch next tile (overlaps MFMA)
            const int ko = (kt + 1) * BK;
#pragma unroll
            for (int p = 0; p < 2; ++p) {
                pa[p] = *(const uint4*)(arow0 + (size_t)p * 32 * KDIM + ko);
                pb[p] = *(const uint4*)(brow0 + (size_t)p * 32 * KDIM + ko);
            }
        }
#pragma unroll
        for (int ks = 0; ks < 2; ++ks) {
            const int kk = ks * 32 + q * 8;
            bf16x8 afrag = *(const bf16x8*)(a_tile + (w * 16 + m) * LDT + kk);
#pragma unroll
            for (int j = 0; j < 4; ++j) {
                bf16x8 bfrag = *(const bf16x8*)(b_tile + (j * 16 + m) * LDT + kk);
                acc[j] = __builtin_amdgcn_mfma_f32_16x16x32_bf16(afrag, bfrag, acc[j], 0, 0, 0);
            }
        }
    }

    // Epilogue: C/D layout col = lane&15, row = (lane>>4)*4 + reg (verified m89/m91)
    float* gp = g_part + ((size_t)kz << 18);
    const int col = lane & 15;
    const int rq  = (lane >> 4) * 4;
#pragma unroll
    for (int j = 0; j < 4; ++j) {
#pragma unroll
        for (int reg = 0; reg < 4; ++reg) {
            const int rg = bm * 64 + w * 16 + rq + reg;
            const int cg = bn * 64 + j * 16 + col;
            gp[rg * CH + cg] = acc[j][reg];
        }
    }
}

// ---------------------------------------------------------------- reduce -----
// g_full = sum of 4 split-K slices. 65536 threads x 1 float4.
__global__ __launch_bounds__(256) void reduce_kernel(const float* __restrict__ g_part,
                                                     float* __restrict__ g_full) {
    int t = blockIdx.x * 256 + threadIdx.x;       // 0..65535
    const float4* p = (const float4*)g_part;
    float4 s = p[t];
#pragma unroll
    for (int sl = 1; sl < SPLITK; ++sl) {
        float4 v = p[t + sl * 65536];
        s.x += v.x; s.y += v.y; s.z += v.z; s.w += v.w;
    }
    ((float4*)g_full)[t] = s;
}

// ---------------------------------------------------------------- loss -------
// Round-2 structure (best measured memory path), atomic-free epilogue:
// block partial -> plain store to partials[blk]. 2048 blocks, i = blk>>2.
__global__ __launch_bounds__(256) void loss_kernel(const float* __restrict__ target,
                                                   const float* __restrict__ g_full,
                                                   float* __restrict__ partials) {
    const float gscale = 1.0f / 1048576.0f;          // 1/(b*local_ch*w*h)
    const float lscale = 1.0e6f / 33554432.0f;       // WEIGHT / count

    const int tid  = threadIdx.x;
    const int lane = tid & 63;
    const int wv   = tid >> 6;
    const int blk  = blockIdx.x;
    const int i    = blk >> 2;                       // 4 blocks per i

    // column indices identical for every row this thread touches
    int col[4];
#pragma unroll
    for (int n = 0; n < 4; ++n) col[n] = (i + 4 * lane + n) & 511;

    const float4* t4 = (const float4*)target;
    float acc = 0.0f;

#pragma unroll
    for (int j = 0; j < 4; ++j) {
        float4 tv[4];
        float  g[4][4];
#pragma unroll
        for (int k = 0; k < 4; ++k) {
            const int idx4 = blk * 4096 + j * 1024 + k * 256 + tid;
            tv[k] = t4[idx4];
            const int a   = (blk & 3) * 64 + j * 16 + k * 4 + wv;   // = (idx4>>6)&255
            const int row = (i + a) & 511;
            const float* grow = g_full + row * CH;
#pragma unroll
            for (int n = 0; n < 4; ++n) g[k][n] = grow[col[n]];
        }
#pragma unroll
        for (int k = 0; k < 4; ++k) {
            float d0 = __builtin_fmaf(g[k][0], gscale, -tv[k].x);
            float d1 = __builtin_fmaf(g[k][1], gscale, -tv[k].y);
            float d2 = __builtin_fmaf(g[k][2], gscale, -tv[k].z);
            float d3 = __builtin_fmaf(g[k][3], gscale, -tv[k].w);
            acc += d0 * d0 + d1 * d1 + d2 * d2 + d3 * d3;
        }
    }

    // wave reduce, then cross-wave via LDS, ONE plain store per block (no atomics)
#pragma unroll
    for (int off = 32; off > 0; off >>= 1) acc += __shfl_xor(acc, off, 64);
    __shared__ float wsum[4];
    if (lane == 0) wsum[wv] = acc;
    __syncthreads();
    if (tid == 0)
        partials[blk] = (wsum[0] + wsum[1] + wsum[2] + wsum[3]) * lscale;
}

// ---------------------------------------------------------------- finish -----
// Sum 2048 partials in one block; plain store to out (no memset needed).
__global__ __launch_bounds__(256) void finish_kernel(const float* __restrict__ partials,
                                                     float* __restrict__ out) {
    const int tid  = threadIdx.x;
    const int lane = tid & 63;
    const int wv   = tid >> 6;
    const float4* p = (const float4*)partials;       // 512 float4
    float4 a = p[tid], b = p[tid + 256];
    float s = a.x + a.y + a.z + a.w + b.x + b.y + b.z + b.w;
#pragma unroll
    for (int off = 32; off > 0; off >>= 1) s += __shfl_xor(s, off, 64);
    __shared__ float wsum[4];
    if (lane == 0) wsum[wv] = s;
    __syncthreads();
    if (tid == 0) out[0] = wsum[0] + wsum[1] + wsum[2] + wsum[3];
}

// ---------------------------------------------------------------- launch -----
extern "C" void kernel_launch(void* const* d_in, const int* in_sizes, int n_in,
                              void* d_out, int out_size, void* d_ws, size_t ws_size,
                              hipStream_t stream) {
    const float* x      = (const float*)d_in[0];   // 2097152 fp32
    const float* target = (const float*)d_in[1];   // 33554432 fp32
    float* out = (float*)d_out;

    __hip_bfloat16* feats = (__hip_bfloat16*)d_ws;                        // 4 MB
    float* g_part   = (float*)((char*)d_ws + FEATS_ELEMS * sizeof(__hip_bfloat16)); // 4 MB
    float* g_full   = g_part + SPLITK * CH * CH;                          // 1 MB
    float* partials = g_full + CH * CH;                                   // 8 KB

    convert_kernel<<<FEATS_ELEMS / (256 * 8), 256, 0, stream>>>(x, feats);
    gemm_kernel<<<dim3(CH / BM, CH / BM, SPLITK), 256, 0, stream>>>(feats, g_part);
    reduce_kernel<<<CH * CH / 4 / 256, 256, 0, stream>>>(g_part, g_full);
    loss_kernel<<<LOSS_BLOCKS, 256, 0, stream>>>(target, g_full, partials);
    finish_kernel<<<1, 256, 0, stream>>>(partials, out);
}